// Round 8
// baseline (96.947 us; speedup 1.0000x reference)
//
#include <hip/hip_runtime.h>
#include <math.h>

#define D_DIM 160
#define H_DIM 192
#define W_DIM 192
#define HWN   (H_DIM * W_DIM)                 // 36864
#define NTOT  ((size_t)D_DIM * H_DIM * W_DIM) // 5898240

#define C1 0.0001f   // 0.01^2
#define C2 0.0009f   // 0.03^2

#define HSEG 16                    // output rows per wave
#define NHSEG (H_DIM / HSEG)       // 12
#define NWAVES (NHSEG * 3 * D_DIM) // 5760
#define MARCH (HSEG + 10)          // 26 input rows per wave
#define NPAIR (MARCH / 2)          // 13 pair-steps

#define DC 22                      // pass2 d-outputs per block
#define DCHUNKS 8                  // 8*22 = 176 >= 160

struct GaussW { float g[11]; };

__device__ __forceinline__ int clampi(int v, int lo, int hi) {
    return min(max(v, lo), hi);
}

// Pass 1 v7: fully-unrolled H-march, TWO ROWS PER STEP, depth-1-pair
// (= 4 rows / 8 loads) register prefetch. Per pair-step: issue next-next
// pair's global loads, stage both rows in LDS (invalid rows as zeros),
// one barrier pair, 22 interleaved ds_read_b64 + 2x W-blur, ring-accumulate
// both rows (constexpr indices), emit up to 2 completed output rows.
template<int P>
__device__ __forceinline__ void p1_pairs(
    const float* __restrict__ pa1, const float* __restrict__ pa2,
    const float* __restrict__ pb1, const float* __restrict__ pb2,
    float* __restrict__ ep, float2* __restrict__ srowA,
    float2* __restrict__ srowB,
    const int lane, const bool va, const bool vb,
    const int hbase, const GaussW& gw, float (&acc)[5][HSEG],
    float2 c0v, float2 c0u, float2 c1v, float2 c1u,
    float2 n0v, float2 n0u, float2 n1v, float2 n1u)
{
    if constexpr (P < NPAIR) {
        // prefetch pair P+2 (rows 2P+4, 2P+5) — in flight across 2 steps
        float2 f0v = {0.f, 0.f}, f0u = {0.f, 0.f};
        float2 f1v = {0.f, 0.f}, f1u = {0.f, 0.f};
        if constexpr (P + 2 < NPAIR) {
            const int h0c = clampi(hbase - 5 + 2 * P + 4, 0, H_DIM - 1);
            const int h1c = clampi(hbase - 5 + 2 * P + 5, 0, H_DIM - 1);
            const size_t r0 = (size_t)h0c * W_DIM;
            const size_t r1 = (size_t)h1c * W_DIM;
            f0v.x = pa1[r0]; f0v.y = pa2[r0];
            f0u.x = pb1[r0]; f0u.y = pb2[r0];
            f1v.x = pa1[r1]; f1v.y = pa2[r1];
            f1u.x = pb1[r1]; f1u.y = pb2[r1];
        }

        constexpr int J0 = 2 * P, J1 = 2 * P + 1;
        const int hin0 = hbase - 5 + J0;
        const int hin1 = hbase - 5 + J1;
        const bool ok0 = (hin0 >= 0) && (hin0 < H_DIM);
        const bool ok1 = (hin1 >= 0) && (hin1 < H_DIM);

        const float2 zz = {0.f, 0.f};
        __builtin_amdgcn_wave_barrier();        // fence vs prev step's reads
        srowA[lane] = (ok0 && va) ? c0v : zz;
        srowB[lane] = (ok1 && va) ? c1v : zz;
        if (lane < 10) {
            srowA[64 + lane] = (ok0 && vb) ? c0u : zz;
            srowB[64 + lane] = (ok1 && vb) ? c1u : zz;
        }
        __builtin_amdgcn_wave_barrier();        // fence writes -> reads

        // W-blur both rows, interleaved (2x ILP on DS + VALU)
        float aA0 = 0.f, aA1 = 0.f, aA2 = 0.f, aA3 = 0.f, aA4 = 0.f;
        float aB0 = 0.f, aB1 = 0.f, aB2 = 0.f, aB3 = 0.f, aB4 = 0.f;
#pragma unroll
        for (int k = 0; k < 11; ++k) {
            const float wk = gw.g[k];
            float2 p = srowA[lane + k];
            float2 q = srowB[lane + k];
            float t1 = wk * p.x;
            float t2 = wk * p.y;
            float s1 = wk * q.x;
            float s2 = wk * q.y;
            aA0 += t1;              aB0 += s1;
            aA1 += t2;              aB1 += s2;
            aA2 = fmaf(t1, p.x, aA2); aB2 = fmaf(s1, q.x, aB2);
            aA3 = fmaf(t2, p.y, aA3); aB3 = fmaf(s2, q.y, aB3);
            aA4 = fmaf(t1, p.y, aA4); aB4 = fmaf(s1, q.y, aB4);
        }

        // ring accumulate row J0 (zeros rows contribute 0 — exact zero-pad)
#pragma unroll
        for (int t = 0; t < 11; ++t) {
            const int o = J0 - 10 + t;          // constexpr after unroll
            if (o >= 0 && o < HSEG) {
                const float wgt = gw.g[10 - t];
                acc[0][o] = fmaf(wgt, aA0, acc[0][o]);
                acc[1][o] = fmaf(wgt, aA1, acc[1][o]);
                acc[2][o] = fmaf(wgt, aA2, acc[2][o]);
                acc[3][o] = fmaf(wgt, aA3, acc[3][o]);
                acc[4][o] = fmaf(wgt, aA4, acc[4][o]);
            }
        }
        // ring accumulate row J1
#pragma unroll
        for (int t = 0; t < 11; ++t) {
            const int o = J1 - 10 + t;
            if (o >= 0 && o < HSEG) {
                const float wgt = gw.g[10 - t];
                acc[0][o] = fmaf(wgt, aB0, acc[0][o]);
                acc[1][o] = fmaf(wgt, aB1, acc[1][o]);
                acc[2][o] = fmaf(wgt, aB2, acc[2][o]);
                acc[3][o] = fmaf(wgt, aB3, acc[3][o]);
                acc[4][o] = fmaf(wgt, aB4, acc[4][o]);
            }
        }

        // emit completed output rows (o complete after row o+10 processed)
        if constexpr (J0 >= 10) {
            constexpr int o = J0 - 10;
            const size_t rb = (size_t)o * W_DIM;
            ep[rb]            = acc[0][o];
            ep[NTOT + rb]     = acc[1][o];
            ep[2 * NTOT + rb] = acc[2][o];
            ep[3 * NTOT + rb] = acc[3][o];
            ep[4 * NTOT + rb] = acc[4][o];
        }
        if constexpr (J1 >= 10) {
            constexpr int o = J1 - 10;
            const size_t rb = (size_t)o * W_DIM;
            ep[rb]            = acc[0][o];
            ep[NTOT + rb]     = acc[1][o];
            ep[2 * NTOT + rb] = acc[2][o];
            ep[3 * NTOT + rb] = acc[3][o];
            ep[4 * NTOT + rb] = acc[4][o];
        }

        p1_pairs<P + 1>(pa1, pa2, pb1, pb2, ep, srowA, srowB, lane, va, vb,
                        hbase, gw, acc, n0v, n0u, n1v, n1u,
                        f0v, f0u, f1v, f1u);
    }
}

__global__ __launch_bounds__(256, 2) void ssim_pass1(
    const float* __restrict__ img1, const float* __restrict__ img2,
    float* __restrict__ fields, GaussW gw)
{
    __shared__ float2 sxy[4][2][80];

    const int wv   = threadIdx.x >> 6;
    const int lane = threadIdx.x & 63;
    const int wid  = blockIdx.x * 4 + wv;
    const int hseg = wid % NHSEG;
    const int t    = wid / NHSEG;
    const int wtile = t % 3;
    const int d     = t / 3;
    const int w0    = wtile * 64;
    const int hbase = hseg * HSEG;

    const int  cola = w0 - 5 + lane;                 // stage col 1
    const bool va   = (cola >= 0) && (cola < W_DIM);
    const int  colb = w0 + 59 + lane;                // stage col 2 (lane<10)
    const bool vb   = (lane < 10) && (colb < W_DIM);
    const int  colac = clampi(cola, 0, W_DIM - 1);   // clamped (masked lanes)
    const int  colbc = min(colb, W_DIM - 1);

    const size_t plane = (size_t)d * HWN;
    const float* pa1 = img1 + plane + colac;
    const float* pa2 = img2 + plane + colac;
    const float* pb1 = img1 + plane + colbc;
    const float* pb2 = img2 + plane + colbc;

    float acc[5][HSEG];
#pragma unroll
    for (int f = 0; f < 5; ++f)
#pragma unroll
        for (int o = 0; o < HSEG; ++o) acc[f][o] = 0.f;

    // prologue: load pairs 0 (rows 0,1) and 1 (rows 2,3)
    float2 c0v, c0u, c1v, c1u, n0v, n0u, n1v, n1u;
    {
        const int h0 = clampi(hbase - 5, 0, H_DIM - 1);
        const int h1 = clampi(hbase - 4, 0, H_DIM - 1);
        const int h2 = clampi(hbase - 3, 0, H_DIM - 1);
        const int h3 = clampi(hbase - 2, 0, H_DIM - 1);
        const size_t r0 = (size_t)h0 * W_DIM, r1 = (size_t)h1 * W_DIM;
        const size_t r2 = (size_t)h2 * W_DIM, r3 = (size_t)h3 * W_DIM;
        c0v.x = pa1[r0]; c0v.y = pa2[r0]; c0u.x = pb1[r0]; c0u.y = pb2[r0];
        c1v.x = pa1[r1]; c1v.y = pa2[r1]; c1u.x = pb1[r1]; c1u.y = pb2[r1];
        n0v.x = pa1[r2]; n0v.y = pa2[r2]; n0u.x = pb1[r2]; n0u.y = pb2[r2];
        n1v.x = pa1[r3]; n1v.y = pa2[r3]; n1u.x = pb1[r3]; n1u.y = pb2[r3];
    }

    float* ep = fields + plane + (size_t)hbase * W_DIM + (w0 + lane);

    p1_pairs<0>(pa1, pa2, pb1, pb2, ep, sxy[wv][0], sxy[wv][1], lane, va, vb,
                hbase, gw, acc, c0v, c0u, c1v, c1u, n0v, n0u, n1v, n1u);
}

// Pass 2: rolling-window D-blur + SSIM + block reduce -> double atomic.
__global__ __launch_bounds__(256) void ssim_pass2(
    const float* __restrict__ fields, double* __restrict__ accum, GaussW gwts)
{
    const int hw = blockIdx.x * 256 + threadIdx.x;
    const int d0 = blockIdx.y * DC;

    float win[5][11];
#pragma unroll
    for (int i = 0; i < 10; ++i) {
        int p = d0 - 5 + i;
        bool ok = (p >= 0) && (p < D_DIM);
        size_t off = (size_t)(ok ? p : 0) * HWN + hw;
#pragma unroll
        for (int f = 0; f < 5; ++f)
            win[f][i] = ok ? fields[(size_t)f * NTOT + off] : 0.f;
    }

    float ssum = 0.f;
#pragma unroll
    for (int j = 0; j < DC; ++j) {
        const int d = d0 + j;
        {
            int p = d + 5;
            bool ok = (p < D_DIM);
            size_t off = (size_t)(ok ? p : 0) * HWN + hw;
#pragma unroll
            for (int f = 0; f < 5; ++f)
                win[f][(j + 10) % 11] = ok ? fields[(size_t)f * NTOT + off] : 0.f;
        }
        if (d < D_DIM) {
            float m[5];
#pragma unroll
            for (int f = 0; f < 5; ++f) {
                float acc = 0.f;
#pragma unroll
                for (int k = 0; k < 11; ++k)
                    acc += gwts.g[k] * win[f][(j + k) % 11];
                m[f] = acc;
            }
            float mu1sq = m[0] * m[0];
            float mu2sq = m[1] * m[1];
            float mu12  = m[0] * m[1];
            float s1sq  = m[2] - mu1sq;
            float s2sq  = m[3] - mu2sq;
            float s12   = m[4] - mu12;
            ssum += ((2.f * mu12 + C1) * (2.f * s12 + C2)) /
                    ((mu1sq + mu2sq + C1) * (s1sq + s2sq + C2));
        }
    }

    for (int off = 32; off > 0; off >>= 1)
        ssum += __shfl_down(ssum, off, 64);
    __shared__ float wsum[4];
    int lane = threadIdx.x & 63;
    int wvx  = threadIdx.x >> 6;
    if (lane == 0) wsum[wvx] = ssum;
    __syncthreads();
    if (threadIdx.x == 0) {
        float bs = wsum[0] + wsum[1] + wsum[2] + wsum[3];
        atomicAdd(accum, (double)bs);
    }
}

__global__ void ssim_finalize(const double* __restrict__ accum,
                              float* __restrict__ out)
{
    out[0] = (float)(accum[0] / (double)NTOT);
}

extern "C" void kernel_launch(void* const* d_in, const int* in_sizes, int n_in,
                              void* d_out, int out_size, void* d_ws, size_t ws_size,
                              hipStream_t stream)
{
    const float* img1 = (const float*)d_in[0];
    const float* img2 = (const float*)d_in[1];
    float* out = (float*)d_out;

    GaussW gwts;
    {
        double raw[11], sum = 0.0;
        for (int i = 0; i < 11; ++i) {
            double x = (double)i - 5.0;
            raw[i] = exp(-(x * x) / (2.0 * 1.5 * 1.5));
            sum += raw[i];
        }
        for (int i = 0; i < 11; ++i) gwts.g[i] = (float)(raw[i] / sum);
    }

    float* fields = (float*)d_ws;                          // 5 * NTOT floats
    double* accum = (double*)((char*)d_ws + 5 * NTOT * 4); // 8B, 8-aligned

    hipMemsetAsync(accum, 0, sizeof(double), stream);

    ssim_pass1<<<NWAVES / 4, 256, 0, stream>>>(img1, img2, fields, gwts);

    dim3 g2(HWN / 256, DCHUNKS); // (144, 8)
    ssim_pass2<<<g2, 256, 0, stream>>>(fields, accum, gwts);

    ssim_finalize<<<1, 1, 0, stream>>>(accum, out);
}

// Round 9
// 85.295 us; speedup vs baseline: 1.1366x; 1.1366x over previous
//
#include <hip/hip_runtime.h>
#include <math.h>

#define D_DIM 160
#define H_DIM 192
#define W_DIM 192
#define HWN   (H_DIM * W_DIM)                 // 36864
#define NTOT  ((size_t)D_DIM * H_DIM * W_DIM) // 5898240

#define C1 0.0001f   // 0.01^2
#define C2 0.0009f   // 0.03^2

#define HSEG 16                    // output rows per wave
#define NHSEG (H_DIM / HSEG)       // 12
#define NWAVES (NHSEG * 3 * D_DIM) // 5760
#define MARCH (HSEG + 10)          // 26 input rows per wave

#define DC 22                      // pass2 d-outputs per block
#define DCHUNKS 8                  // 8*22 = 176 >= 160

struct GaussW { float g[11]; };

__device__ __forceinline__ int clampi(int v, int lo, int hi) {
    return min(max(v, lo), hi);
}

// Pass 1 v8: fully-unrolled H-march, single-row steps (R7's proven
// 0-conflict LDS pattern), DOUBLE-BUFFERED LDS row + ONE fence per step
// (ds_write->ds_read spans a full step of FMAs), DEPTH-3 global prefetch
// (12 loads in flight). Step J: issue row J+3 loads; barrier; write row
// J+1 (regs) into buf[(J+1)&1]; read row J from buf[J&1]; W-blur; ring
// accumulate (constexpr indices); emit output row J-10.
template<int J>
__device__ __forceinline__ void p1_steps(
    const float* __restrict__ pa1, const float* __restrict__ pa2,
    const float* __restrict__ pb1, const float* __restrict__ pb2,
    float2* __restrict__ ep01, float2* __restrict__ ep23,
    float* __restrict__ ep4,
    float2* __restrict__ sbuf0, float2* __restrict__ sbuf1,
    const int lane, const bool va, const bool vb,
    const int hbase, const GaussW& gw, float (&acc)[5][HSEG],
    float2 wAv, float2 wAu, float2 wBv, float2 wBu)
{
    if constexpr (J < MARCH) {
        // issue prefetch for row J+3 (in flight across ~3 steps)
        float2 pfv = {0.f, 0.f}, pfu = {0.f, 0.f};
        if constexpr (J + 3 < MARCH) {
            const int hc = clampi(hbase - 5 + J + 3, 0, H_DIM - 1);
            const size_t ro = (size_t)hc * W_DIM;
            pfv.x = pa1[ro]; pfv.y = pa2[ro];
            pfu.x = pb1[ro]; pfu.y = pb2[ro];
        }

        __builtin_amdgcn_wave_barrier();    // one fence per step

        // stage row J+1 into the other buffer (masked to zero outside)
        if constexpr (J + 1 < MARCH) {
            const int h1 = hbase - 5 + (J + 1);
            const bool ok1 = (h1 >= 0) && (h1 < H_DIM);   // wave-uniform
            float2* wb = ((J + 1) & 1) ? sbuf1 : sbuf0;
            const float2 zz = {0.f, 0.f};
            wb[lane] = (ok1 && va) ? wAv : zz;
            if (lane < 10) wb[64 + lane] = (ok1 && vb) ? wAu : zz;
        }

        // read row J (staged last step, write->read latency already hidden)
        const int hin = hbase - 5 + J;
        if (hin >= 0 && hin < H_DIM) {      // wave-uniform
            const float2* rb = (J & 1) ? sbuf1 : sbuf0;

            float a0 = 0.f, a1 = 0.f, a2 = 0.f, a3 = 0.f, a4 = 0.f;
#pragma unroll
            for (int k = 0; k < 11; ++k) {
                float2 p = rb[lane + k];
                float t1 = gw.g[k] * p.x;
                float t2 = gw.g[k] * p.y;
                a0 += t1;
                a1 += t2;
                a2 = fmaf(t1, p.x, a2);
                a3 = fmaf(t2, p.y, a3);
                a4 = fmaf(t1, p.y, a4);
            }

            // row J feeds outputs o = J-10 .. J with weight g[J-o]
#pragma unroll
            for (int t = 0; t < 11; ++t) {
                const int o = J - 10 + t;   // constexpr after unroll
                if (o >= 0 && o < HSEG) {
                    const float wgt = gw.g[10 - t];
                    acc[0][o] = fmaf(wgt, a0, acc[0][o]);
                    acc[1][o] = fmaf(wgt, a1, acc[1][o]);
                    acc[2][o] = fmaf(wgt, a2, acc[2][o]);
                    acc[3][o] = fmaf(wgt, a3, acc[3][o]);
                    acc[4][o] = fmaf(wgt, a4, acc[4][o]);
                }
            }
        }

        // output row o = J-10 complete after step J
        if constexpr (J >= 10) {
            constexpr int o = J - 10;
            const size_t rb_ = (size_t)o * W_DIM;
            float2 v01; v01.x = acc[0][o]; v01.y = acc[1][o];
            float2 v23; v23.x = acc[2][o]; v23.y = acc[3][o];
            ep01[rb_] = v01;
            ep23[rb_] = v23;
            ep4[rb_]  = acc[4][o];
        }

        p1_steps<J + 1>(pa1, pa2, pb1, pb2, ep01, ep23, ep4, sbuf0, sbuf1,
                        lane, va, vb, hbase, gw, acc, wBv, wBu, pfv, pfu);
    }
}

__global__ __launch_bounds__(256, 2) void ssim_pass1(
    const float* __restrict__ img1, const float* __restrict__ img2,
    float2* __restrict__ f01, float2* __restrict__ f23,
    float* __restrict__ f4, GaussW gw)
{
    __shared__ float2 sxy[4][2][80];

    const int wv   = threadIdx.x >> 6;
    const int lane = threadIdx.x & 63;
    const int wid  = blockIdx.x * 4 + wv;
    const int hseg = wid % NHSEG;
    const int t    = wid / NHSEG;
    const int wtile = t % 3;
    const int d     = t / 3;
    const int w0    = wtile * 64;
    const int hbase = hseg * HSEG;

    const int  cola = w0 - 5 + lane;                 // stage col 1
    const bool va   = (cola >= 0) && (cola < W_DIM);
    const int  colb = w0 + 59 + lane;                // stage col 2 (lane<10)
    const bool vb   = (lane < 10) && (colb < W_DIM);
    const int  colac = clampi(cola, 0, W_DIM - 1);   // clamped (masked lanes)
    const int  colbc = min(colb, W_DIM - 1);

    const size_t plane = (size_t)d * HWN;
    const float* pa1 = img1 + plane + colac;
    const float* pa2 = img2 + plane + colac;
    const float* pb1 = img1 + plane + colbc;
    const float* pb2 = img2 + plane + colbc;

    float acc[5][HSEG];
#pragma unroll
    for (int f = 0; f < 5; ++f)
#pragma unroll
        for (int o = 0; o < HSEG; ++o) acc[f][o] = 0.f;

    float2* sbuf0 = sxy[wv][0];
    float2* sbuf1 = sxy[wv][1];

    // prologue: load rows 0,1,2; stage row 0 into buf[0]
    float2 r0v, r0u, r1v, r1u, r2v, r2u;
    {
        const int h0 = clampi(hbase - 5, 0, H_DIM - 1);
        const int h1 = clampi(hbase - 4, 0, H_DIM - 1);
        const int h2 = clampi(hbase - 3, 0, H_DIM - 1);
        const size_t q0 = (size_t)h0 * W_DIM;
        const size_t q1 = (size_t)h1 * W_DIM;
        const size_t q2 = (size_t)h2 * W_DIM;
        r0v.x = pa1[q0]; r0v.y = pa2[q0]; r0u.x = pb1[q0]; r0u.y = pb2[q0];
        r1v.x = pa1[q1]; r1v.y = pa2[q1]; r1u.x = pb1[q1]; r1u.y = pb2[q1];
        r2v.x = pa1[q2]; r2v.y = pa2[q2]; r2u.x = pb1[q2]; r2u.y = pb2[q2];
    }
    {
        const bool ok0 = (hbase - 5 >= 0);           // wave-uniform
        const float2 zz = {0.f, 0.f};
        sbuf0[lane] = (ok0 && va) ? r0v : zz;
        if (lane < 10) sbuf0[64 + lane] = (ok0 && vb) ? r0u : zz;
    }

    const size_t ebase = plane + (size_t)hbase * W_DIM + (w0 + lane);
    float2* ep01 = f01 + ebase;
    float2* ep23 = f23 + ebase;
    float*  ep4  = f4  + ebase;

    p1_steps<0>(pa1, pa2, pb1, pb2, ep01, ep23, ep4, sbuf0, sbuf1,
                lane, va, vb, hbase, gw, acc, r1v, r1u, r2v, r2u);
}

// Pass 2: rolling-window D-blur + SSIM + block reduce -> double atomic.
// Fields in (float2, float2, float) layout: 3 loads per plane instead of 5.
__global__ __launch_bounds__(256) void ssim_pass2(
    const float2* __restrict__ f01, const float2* __restrict__ f23,
    const float* __restrict__ f4, double* __restrict__ accum, GaussW gwts)
{
    const int hw = blockIdx.x * 256 + threadIdx.x;
    const int d0 = blockIdx.y * DC;

    float2 w01[11], w23[11];
    float  w4[11];
#pragma unroll
    for (int i = 0; i < 10; ++i) {
        int p = d0 - 5 + i;
        bool ok = (p >= 0) && (p < D_DIM);
        size_t off = (size_t)(ok ? p : 0) * HWN + hw;
        float2 zz = {0.f, 0.f};
        w01[i] = ok ? f01[off] : zz;
        w23[i] = ok ? f23[off] : zz;
        w4[i]  = ok ? f4[off]  : 0.f;
    }

    float ssum = 0.f;
#pragma unroll
    for (int j = 0; j < DC; ++j) {
        const int d = d0 + j;
        {
            int p = d + 5;
            bool ok = (p < D_DIM);
            size_t off = (size_t)(ok ? p : 0) * HWN + hw;
            float2 zz = {0.f, 0.f};
            w01[(j + 10) % 11] = ok ? f01[off] : zz;
            w23[(j + 10) % 11] = ok ? f23[off] : zz;
            w4[(j + 10) % 11]  = ok ? f4[off]  : 0.f;
        }
        if (d < D_DIM) {
            float m0 = 0.f, m1 = 0.f, m2 = 0.f, m3 = 0.f, m4 = 0.f;
#pragma unroll
            for (int k = 0; k < 11; ++k) {
                const float wk = gwts.g[k];
                const int s = (j + k) % 11;
                m0 = fmaf(wk, w01[s].x, m0);
                m1 = fmaf(wk, w01[s].y, m1);
                m2 = fmaf(wk, w23[s].x, m2);
                m3 = fmaf(wk, w23[s].y, m3);
                m4 = fmaf(wk, w4[s],    m4);
            }
            float mu1sq = m0 * m0;
            float mu2sq = m1 * m1;
            float mu12  = m0 * m1;
            float s1sq  = m2 - mu1sq;
            float s2sq  = m3 - mu2sq;
            float s12   = m4 - mu12;
            ssum += ((2.f * mu12 + C1) * (2.f * s12 + C2)) /
                    ((mu1sq + mu2sq + C1) * (s1sq + s2sq + C2));
        }
    }

    for (int off = 32; off > 0; off >>= 1)
        ssum += __shfl_down(ssum, off, 64);
    __shared__ float wsum[4];
    int lane = threadIdx.x & 63;
    int wvx  = threadIdx.x >> 6;
    if (lane == 0) wsum[wvx] = ssum;
    __syncthreads();
    if (threadIdx.x == 0) {
        float bs = wsum[0] + wsum[1] + wsum[2] + wsum[3];
        atomicAdd(accum, (double)bs);
    }
}

__global__ void ssim_finalize(const double* __restrict__ accum,
                              float* __restrict__ out)
{
    out[0] = (float)(accum[0] / (double)NTOT);
}

extern "C" void kernel_launch(void* const* d_in, const int* in_sizes, int n_in,
                              void* d_out, int out_size, void* d_ws, size_t ws_size,
                              hipStream_t stream)
{
    const float* img1 = (const float*)d_in[0];
    const float* img2 = (const float*)d_in[1];
    float* out = (float*)d_out;

    GaussW gwts;
    {
        double raw[11], sum = 0.0;
        for (int i = 0; i < 11; ++i) {
            double x = (double)i - 5.0;
            raw[i] = exp(-(x * x) / (2.0 * 1.5 * 1.5));
            sum += raw[i];
        }
        for (int i = 0; i < 11; ++i) gwts.g[i] = (float)(raw[i] / sum);
    }

    // workspace layout: f01 (float2[NTOT]) | f23 (float2[NTOT]) | f4 (float[NTOT]) | accum (double)
    float2* f01 = (float2*)d_ws;
    float2* f23 = f01 + NTOT;
    float*  f4  = (float*)((char*)d_ws + 16 * NTOT);
    double* accum = (double*)((char*)d_ws + 20 * NTOT);

    hipMemsetAsync(accum, 0, sizeof(double), stream);

    ssim_pass1<<<NWAVES / 4, 256, 0, stream>>>(img1, img2, f01, f23, f4, gwts);

    dim3 g2(HWN / 256, DCHUNKS); // (144, 8)
    ssim_pass2<<<g2, 256, 0, stream>>>(f01, f23, f4, accum, gwts);

    ssim_finalize<<<1, 1, 0, stream>>>(accum, out);
}

// Round 10
// 85.042 us; speedup vs baseline: 1.1400x; 1.0030x over previous
//
#include <hip/hip_runtime.h>
#include <hip/hip_fp16.h>
#include <math.h>

#define D_DIM 160
#define H_DIM 192
#define W_DIM 192
#define HWN   (H_DIM * W_DIM)                 // 36864
#define NTOT  ((size_t)D_DIM * H_DIM * W_DIM) // 5898240

#define C1 0.0001f   // 0.01^2
#define C2 0.0009f   // 0.03^2

#define HSEG 16                    // output rows per wave
#define NHSEG (H_DIM / HSEG)       // 12
#define NWAVES (NHSEG * 3 * D_DIM) // 5760
#define MARCH (HSEG + 10)          // 26 input rows per wave

#define DC 22                      // pass2 d-outputs per block
#define DCHUNKS 8                  // 8*22 = 176 >= 160

struct GaussW { float g[11]; };

__device__ __forceinline__ int clampi(int v, int lo, int hi) {
    return min(max(v, lo), hi);
}

// Pass 1 v9: R9's proven pipeline (single-row steps, double-buffered LDS row,
// one fence/step, depth-3 global prefetch) + FP16 field output (half2 packed:
// (f0,f1), (f2,f3), f4). Write traffic halved: 115 -> 58 MB.
template<int J>
__device__ __forceinline__ void p1_steps(
    const float* __restrict__ pa1, const float* __restrict__ pa2,
    const float* __restrict__ pb1, const float* __restrict__ pb2,
    __half2* __restrict__ ep01, __half2* __restrict__ ep23,
    __half* __restrict__ ep4,
    float2* __restrict__ sbuf0, float2* __restrict__ sbuf1,
    const int lane, const bool va, const bool vb,
    const int hbase, const GaussW& gw, float (&acc)[5][HSEG],
    float2 wAv, float2 wAu, float2 wBv, float2 wBu)
{
    if constexpr (J < MARCH) {
        // issue prefetch for row J+3 (in flight across ~3 steps)
        float2 pfv = {0.f, 0.f}, pfu = {0.f, 0.f};
        if constexpr (J + 3 < MARCH) {
            const int hc = clampi(hbase - 5 + J + 3, 0, H_DIM - 1);
            const size_t ro = (size_t)hc * W_DIM;
            pfv.x = pa1[ro]; pfv.y = pa2[ro];
            pfu.x = pb1[ro]; pfu.y = pb2[ro];
        }

        __builtin_amdgcn_wave_barrier();    // one fence per step

        // stage row J+1 into the other buffer (masked to zero outside)
        if constexpr (J + 1 < MARCH) {
            const int h1 = hbase - 5 + (J + 1);
            const bool ok1 = (h1 >= 0) && (h1 < H_DIM);   // wave-uniform
            float2* wb = ((J + 1) & 1) ? sbuf1 : sbuf0;
            const float2 zz = {0.f, 0.f};
            wb[lane] = (ok1 && va) ? wAv : zz;
            if (lane < 10) wb[64 + lane] = (ok1 && vb) ? wAu : zz;
        }

        // read row J (staged last step; write->read spans a full step)
        const int hin = hbase - 5 + J;
        if (hin >= 0 && hin < H_DIM) {      // wave-uniform
            const float2* rb = (J & 1) ? sbuf1 : sbuf0;

            float a0 = 0.f, a1 = 0.f, a2 = 0.f, a3 = 0.f, a4 = 0.f;
#pragma unroll
            for (int k = 0; k < 11; ++k) {
                float2 p = rb[lane + k];
                float t1 = gw.g[k] * p.x;
                float t2 = gw.g[k] * p.y;
                a0 += t1;
                a1 += t2;
                a2 = fmaf(t1, p.x, a2);
                a3 = fmaf(t2, p.y, a3);
                a4 = fmaf(t1, p.y, a4);
            }

            // row J feeds outputs o = J-10 .. J with weight g[J-o]
#pragma unroll
            for (int t = 0; t < 11; ++t) {
                const int o = J - 10 + t;   // constexpr after unroll
                if (o >= 0 && o < HSEG) {
                    const float wgt = gw.g[10 - t];
                    acc[0][o] = fmaf(wgt, a0, acc[0][o]);
                    acc[1][o] = fmaf(wgt, a1, acc[1][o]);
                    acc[2][o] = fmaf(wgt, a2, acc[2][o]);
                    acc[3][o] = fmaf(wgt, a3, acc[3][o]);
                    acc[4][o] = fmaf(wgt, a4, acc[4][o]);
                }
            }
        }

        // output row o = J-10 complete after step J -> emit as fp16
        if constexpr (J >= 10) {
            constexpr int o = J - 10;
            const size_t rb_ = (size_t)o * W_DIM;
            float2 v01; v01.x = acc[0][o]; v01.y = acc[1][o];
            float2 v23; v23.x = acc[2][o]; v23.y = acc[3][o];
            ep01[rb_] = __float22half2_rn(v01);
            ep23[rb_] = __float22half2_rn(v23);
            ep4[rb_]  = __float2half_rn(acc[4][o]);
        }

        p1_steps<J + 1>(pa1, pa2, pb1, pb2, ep01, ep23, ep4, sbuf0, sbuf1,
                        lane, va, vb, hbase, gw, acc, wBv, wBu, pfv, pfu);
    }
}

__global__ __launch_bounds__(256, 2) void ssim_pass1(
    const float* __restrict__ img1, const float* __restrict__ img2,
    __half2* __restrict__ f01, __half2* __restrict__ f23,
    __half* __restrict__ f4, GaussW gw)
{
    __shared__ float2 sxy[4][2][80];

    const int wv   = threadIdx.x >> 6;
    const int lane = threadIdx.x & 63;
    const int wid  = blockIdx.x * 4 + wv;
    const int hseg = wid % NHSEG;
    const int t    = wid / NHSEG;
    const int wtile = t % 3;
    const int d     = t / 3;
    const int w0    = wtile * 64;
    const int hbase = hseg * HSEG;

    const int  cola = w0 - 5 + lane;                 // stage col 1
    const bool va   = (cola >= 0) && (cola < W_DIM);
    const int  colb = w0 + 59 + lane;                // stage col 2 (lane<10)
    const bool vb   = (lane < 10) && (colb < W_DIM);
    const int  colac = clampi(cola, 0, W_DIM - 1);   // clamped (masked lanes)
    const int  colbc = min(colb, W_DIM - 1);

    const size_t plane = (size_t)d * HWN;
    const float* pa1 = img1 + plane + colac;
    const float* pa2 = img2 + plane + colac;
    const float* pb1 = img1 + plane + colbc;
    const float* pb2 = img2 + plane + colbc;

    float acc[5][HSEG];
#pragma unroll
    for (int f = 0; f < 5; ++f)
#pragma unroll
        for (int o = 0; o < HSEG; ++o) acc[f][o] = 0.f;

    float2* sbuf0 = sxy[wv][0];
    float2* sbuf1 = sxy[wv][1];

    // prologue: load rows 0,1,2; stage row 0 into buf[0]
    float2 r0v, r0u, r1v, r1u, r2v, r2u;
    {
        const int h0 = clampi(hbase - 5, 0, H_DIM - 1);
        const int h1 = clampi(hbase - 4, 0, H_DIM - 1);
        const int h2 = clampi(hbase - 3, 0, H_DIM - 1);
        const size_t q0 = (size_t)h0 * W_DIM;
        const size_t q1 = (size_t)h1 * W_DIM;
        const size_t q2 = (size_t)h2 * W_DIM;
        r0v.x = pa1[q0]; r0v.y = pa2[q0]; r0u.x = pb1[q0]; r0u.y = pb2[q0];
        r1v.x = pa1[q1]; r1v.y = pa2[q1]; r1u.x = pb1[q1]; r1u.y = pb2[q1];
        r2v.x = pa1[q2]; r2v.y = pa2[q2]; r2u.x = pb1[q2]; r2u.y = pb2[q2];
    }
    {
        const bool ok0 = (hbase - 5 >= 0);           // wave-uniform
        const float2 zz = {0.f, 0.f};
        sbuf0[lane] = (ok0 && va) ? r0v : zz;
        if (lane < 10) sbuf0[64 + lane] = (ok0 && vb) ? r0u : zz;
    }

    const size_t ebase = plane + (size_t)hbase * W_DIM + (w0 + lane);
    __half2* ep01 = f01 + ebase;
    __half2* ep23 = f23 + ebase;
    __half*  ep4  = f4  + ebase;

    p1_steps<0>(pa1, pa2, pb1, pb2, ep01, ep23, ep4, sbuf0, sbuf1,
                lane, va, vb, hbase, gw, acc, r1v, r1u, r2v, r2u);
}

// Pass 2: rolling-window D-blur + SSIM + block reduce -> double atomic.
// FP16 fields, converted to f32 once per load; window kept in f32 regs.
__global__ __launch_bounds__(256) void ssim_pass2(
    const __half2* __restrict__ f01, const __half2* __restrict__ f23,
    const __half* __restrict__ f4, double* __restrict__ accum, GaussW gwts)
{
    const int hw = blockIdx.x * 256 + threadIdx.x;
    const int d0 = blockIdx.y * DC;

    float2 w01[11], w23[11];
    float  w4[11];
#pragma unroll
    for (int i = 0; i < 10; ++i) {
        int p = d0 - 5 + i;
        bool ok = (p >= 0) && (p < D_DIM);
        size_t off = (size_t)(ok ? p : 0) * HWN + hw;
        float2 zz = {0.f, 0.f};
        w01[i] = ok ? __half22float2(f01[off]) : zz;
        w23[i] = ok ? __half22float2(f23[off]) : zz;
        w4[i]  = ok ? __half2float(f4[off])    : 0.f;
    }

    float ssum = 0.f;
#pragma unroll
    for (int j = 0; j < DC; ++j) {
        const int d = d0 + j;
        {
            int p = d + 5;
            bool ok = (p < D_DIM);
            size_t off = (size_t)(ok ? p : 0) * HWN + hw;
            float2 zz = {0.f, 0.f};
            w01[(j + 10) % 11] = ok ? __half22float2(f01[off]) : zz;
            w23[(j + 10) % 11] = ok ? __half22float2(f23[off]) : zz;
            w4[(j + 10) % 11]  = ok ? __half2float(f4[off])    : 0.f;
        }
        if (d < D_DIM) {
            float m0 = 0.f, m1 = 0.f, m2 = 0.f, m3 = 0.f, m4 = 0.f;
#pragma unroll
            for (int k = 0; k < 11; ++k) {
                const float wk = gwts.g[k];
                const int s = (j + k) % 11;
                m0 = fmaf(wk, w01[s].x, m0);
                m1 = fmaf(wk, w01[s].y, m1);
                m2 = fmaf(wk, w23[s].x, m2);
                m3 = fmaf(wk, w23[s].y, m3);
                m4 = fmaf(wk, w4[s],    m4);
            }
            float mu1sq = m0 * m0;
            float mu2sq = m1 * m1;
            float mu12  = m0 * m1;
            float s1sq  = m2 - mu1sq;
            float s2sq  = m3 - mu2sq;
            float s12   = m4 - mu12;
            ssum += ((2.f * mu12 + C1) * (2.f * s12 + C2)) /
                    ((mu1sq + mu2sq + C1) * (s1sq + s2sq + C2));
        }
    }

    for (int off = 32; off > 0; off >>= 1)
        ssum += __shfl_down(ssum, off, 64);
    __shared__ float wsum[4];
    int lane = threadIdx.x & 63;
    int wvx  = threadIdx.x >> 6;
    if (lane == 0) wsum[wvx] = ssum;
    __syncthreads();
    if (threadIdx.x == 0) {
        float bs = wsum[0] + wsum[1] + wsum[2] + wsum[3];
        atomicAdd(accum, (double)bs);
    }
}

__global__ void ssim_finalize(const double* __restrict__ accum,
                              float* __restrict__ out)
{
    out[0] = (float)(accum[0] / (double)NTOT);
}

extern "C" void kernel_launch(void* const* d_in, const int* in_sizes, int n_in,
                              void* d_out, int out_size, void* d_ws, size_t ws_size,
                              hipStream_t stream)
{
    const float* img1 = (const float*)d_in[0];
    const float* img2 = (const float*)d_in[1];
    float* out = (float*)d_out;

    GaussW gwts;
    {
        double raw[11], sum = 0.0;
        for (int i = 0; i < 11; ++i) {
            double x = (double)i - 5.0;
            raw[i] = exp(-(x * x) / (2.0 * 1.5 * 1.5));
            sum += raw[i];
        }
        for (int i = 0; i < 11; ++i) gwts.g[i] = (float)(raw[i] / sum);
    }

    // workspace: h01 (half2[NTOT]) | h23 (half2[NTOT]) | h4 (half[NTOT]) | accum
    __half2* h01 = (__half2*)d_ws;
    __half2* h23 = h01 + NTOT;
    __half*  h4  = (__half*)(h23 + NTOT);
    double* accum = (double*)((char*)d_ws + 10 * NTOT);  // 10*NTOT % 8 == 0

    hipMemsetAsync(accum, 0, sizeof(double), stream);

    ssim_pass1<<<NWAVES / 4, 256, 0, stream>>>(img1, img2, h01, h23, h4, gwts);

    dim3 g2(HWN / 256, DCHUNKS); // (144, 8)
    ssim_pass2<<<g2, 256, 0, stream>>>(h01, h23, h4, accum, gwts);

    ssim_finalize<<<1, 1, 0, stream>>>(accum, out);
}